// Round 1
// baseline (2181.896 us; speedup 1.0000x reference)
//
#include <hip/hip_runtime.h>
#include <stdint.h>

#define NDIM 16384

typedef float  fvec4  __attribute__((ext_vector_type(4)));
typedef float  f32x4  __attribute__((ext_vector_type(4)));
typedef __bf16 bf16x8 __attribute__((ext_vector_type(8)));
typedef unsigned short u16x8 __attribute__((ext_vector_type(8)));
typedef unsigned short u16x4 __attribute__((ext_vector_type(4)));

static_assert(sizeof(bf16x8) == 16, "bf16x8 must be 16B");
static_assert(sizeof(u16x8) == 16, "u16x8 must be 16B");

// ---------- helpers ----------

__device__ __forceinline__ unsigned short bf16r(float x) {
  unsigned u = __builtin_bit_cast(unsigned, x);
  return (unsigned short)((u + 0x7FFFu + ((u >> 16) & 1u)) >> 16);
}

__device__ __forceinline__ void split2(float v, unsigned short& h, unsigned short& l) {
  h = bf16r(v);
  float hf = __builtin_bit_cast(float, (unsigned)h << 16);
  l = bf16r(v - hf);
}

// global -> LDS direct copy, 16B per lane (linear dest per wave)
__device__ __forceinline__ void gload_lds16(const void* g, void* l) {
  typedef __attribute__((address_space(1))) const unsigned int gas_u32;
  typedef __attribute__((address_space(3))) unsigned int las_u32;
  __builtin_amdgcn_global_load_lds((gas_u32*)(uintptr_t)g,
                                   (las_u32*)(unsigned)(uintptr_t)l, 16, 0, 0);
}

// =====================================================================
// K1: fused linears: q->Bpack(swizzled split bf16), k->Apack(split bf16),
//     Am = x@Wm1a^T, Bm = x@Wm1b^T + bm1, XU = x@Wu1a^T + bu1
// block: 256 thr, 64 rows. LDS: xs[64][128] (quad-swizzled) + wT[128][128]
// =====================================================================
__global__ __launch_bounds__(256, 1) void k1_linears(
    const float* __restrict__ x,
    const float* __restrict__ Wq, const float* __restrict__ bq,
    const float* __restrict__ Wk, const float* __restrict__ bk,
    const float* __restrict__ Wm1, const float* __restrict__ bm1,
    const float* __restrict__ Wu1, const float* __restrict__ bu1,
    unsigned short* __restrict__ Apack, unsigned short* __restrict__ Bpack,
    float* __restrict__ Am, float* __restrict__ Bm, float* __restrict__ XU)
{
  extern __shared__ char lds[];
  float* xs = (float*)lds;              // 32768 B, [64][128] quad-swizzled
  float* wT = (float*)(lds + 32768);    // 65536 B, [c][co]

  const int t = threadIdx.x;
  const int rbase = blockIdx.x * 64;
  const int tr = t >> 4, tc = t & 15;

  // stage xs (swizzle float4-quads by row>>2)
#pragma unroll
  for (int i = 0; i < 8; ++i) {
    int flat = (i * 256 + t) * 4;  // dword index in [64][128]
    int row = flat >> 7, c = flat & 127;
    fvec4 v = *(const fvec4*)(x + (size_t)(rbase + row) * 128 + c);
    int q = (c >> 2) ^ ((row >> 2) & 7);
    *(fvec4*)(xs + row * 128 + q * 4) = v;
  }

  for (int s = 0; s < 5; ++s) {
    const float* W; int wstride, coff; const float* bias;
    if (s == 0)      { W = Wq;  wstride = 128; coff = 0;   bias = bq; }
    else if (s == 1) { W = Wk;  wstride = 128; coff = 0;   bias = bk; }
    else if (s == 2) { W = Wm1; wstride = 256; coff = 0;   bias = nullptr; }
    else if (s == 3) { W = Wm1; wstride = 256; coff = 128; bias = bm1; }
    else             { W = Wu1; wstride = 256; coff = 0;   bias = bu1; }

    __syncthreads();  // prev gemm reads done (and xs staged on s==0)
    // stage wT transposed: thread t handles row co=t>>1, half (t&1)*64
    {
      int co = t >> 1, c0 = (t & 1) * 64;
      const float* wr = W + (size_t)co * wstride + coff + c0;
#pragma unroll
      for (int i = 0; i < 16; ++i) {
        fvec4 v = *(const fvec4*)(wr + 4 * i);
        wT[(c0 + 4 * i + 0) * 128 + co] = v[0];
        wT[(c0 + 4 * i + 1) * 128 + co] = v[1];
        wT[(c0 + 4 * i + 2) * 128 + co] = v[2];
        wT[(c0 + 4 * i + 3) * 128 + co] = v[3];
      }
    }
    __syncthreads();

    float acc[4][8];
#pragma unroll
    for (int rr = 0; rr < 4; ++rr)
#pragma unroll
      for (int i = 0; i < 8; ++i) acc[rr][i] = 0.f;

    for (int cq = 0; cq < 32; ++cq) {
      fvec4 xv[4];
#pragma unroll
      for (int rr = 0; rr < 4; ++rr)
        xv[rr] = *(const fvec4*)(xs + (tr * 4 + rr) * 128 + ((cq ^ (tr & 7)) << 2));
#pragma unroll
      for (int j = 0; j < 4; ++j) {
        int c = cq * 4 + j;
        fvec4 wa = *(const fvec4*)(wT + c * 128 + tc * 4);
        fvec4 wb = *(const fvec4*)(wT + c * 128 + 64 + tc * 4);
#pragma unroll
        for (int rr = 0; rr < 4; ++rr) {
          float xj = xv[rr][j];
#pragma unroll
          for (int i = 0; i < 4; ++i) {
            acc[rr][i]     += xj * wa[i];
            acc[rr][4 + i] += xj * wb[i];
          }
        }
      }
    }

    float ba[4] = {0, 0, 0, 0}, bb[4] = {0, 0, 0, 0};
    if (bias) {
      fvec4 t0 = *(const fvec4*)(bias + tc * 4);
      fvec4 t1 = *(const fvec4*)(bias + 64 + tc * 4);
#pragma unroll
      for (int i = 0; i < 4; ++i) { ba[i] = t0[i]; bb[i] = t1[i]; }
    }

#pragma unroll
    for (int rr = 0; rr < 4; ++rr) {
      int row = rbase + tr * 4 + rr;
      float v0[4], v1[4];
#pragma unroll
      for (int i = 0; i < 4; ++i) {
        v0[i] = acc[rr][i] + ba[i];
        v1[i] = acc[rr][4 + i] + bb[i];
      }
      if (s >= 2) {
        float* dst = (s == 2 ? Am : (s == 3 ? Bm : XU)) + (size_t)row * 128;
        fvec4 w0 = {v0[0], v0[1], v0[2], v0[3]};
        fvec4 w1 = {v1[0], v1[1], v1[2], v1[3]};
        *(fvec4*)(dst + tc * 4) = w0;
        *(fvec4*)(dst + 64 + tc * 4) = w1;
      } else {
        unsigned short h0[4], l0[4], h1[4], l1[4];
#pragma unroll
        for (int i = 0; i < 4; ++i) { split2(v0[i], h0[i], l0[i]); split2(v1[i], h1[i], l1[i]); }
        u16x4 H0 = {h0[0], h0[1], h0[2], h0[3]};
        u16x4 H1 = {h1[0], h1[1], h1[2], h1[3]};
        u16x4 L0 = {l0[0], l0[1], l0[2], l0[3]};
        u16x4 L1 = {l1[0], l1[1], l1[2], l1[3]};
        if (s == 1) {  // k -> Apack, plain layout [hi(128) | lo(128)]
          unsigned short* dst = Apack + (size_t)row * 256;
          *(u16x4*)(dst + tc * 4) = H0;
          *(u16x4*)(dst + 64 + tc * 4) = H1;
          *(u16x4*)(dst + 128 + tc * 4) = L0;
          *(u16x4*)(dst + 192 + tc * 4) = L1;
        } else {       // q -> Bpack, group-swizzled for LDS bank spread
          int jm = row & 7;
          int p0 = (((tc >> 1) ^ jm) << 3) | ((tc & 1) << 2);
          int p1 = (((8 + (tc >> 1)) ^ jm) << 3) | ((tc & 1) << 2);
          unsigned short* dst = Bpack + (size_t)row * 256;
          *(u16x4*)(dst + p0) = H0;
          *(u16x4*)(dst + p1) = H1;
          *(u16x4*)(dst + 128 + p0) = L0;
          *(u16x4*)(dst + 128 + p1) = L1;
        }
      }
    }
  }
}

// =====================================================================
// K2: fused split-bf16 GEMM (K=384) + streaming top-20 per row.
// grid 256 = 128 row-tiles x 2 j-halves. block 256 thr (4 waves 2x2),
// wave tile 64x64 (4x4 frags of 16x16x32). A-frags in registers.
// =====================================================================
__global__ __launch_bounds__(256, 1) void k2_simtopk(
    const unsigned short* __restrict__ Apack, const unsigned short* __restrict__ Bpack,
    float* __restrict__ plv, int* __restrict__ pli)
{
  extern __shared__ char lds[];
  char* Bs = lds;                                   // 2 x 32768
  float* simbuf = (float*)(lds + 65536);            // [128][129]
  float* maxbuf = (float*)(lds + 131584);           // [128][2]
  unsigned char* flags = (unsigned char*)(lds + 132608);  // [128]
  int* anyflag = (int*)(lds + 132736);

  const int t = threadIdx.x;
  const int lane = t & 63, wid = t >> 6;
  const int wi = wid >> 1, wj = wid & 1;
  const int tile = blockIdx.x >> 1, jhalf = blockIdx.x & 1;
  const int rbase = tile * 128;
  const int jstart = jhalf * 8192;
  const int l15 = lane & 15, kg = lane >> 4;

  if (t < 128) flags[t] = 0;
  if (t == 0) *anyflag = 0;

  // ---- A fragments in registers (hi 4 ksteps + lo 4 ksteps, per mi) ----
  u16x8 Ahi[4][4], Alo[4][4];
#pragma unroll
  for (int mi = 0; mi < 4; ++mi) {
    const unsigned short* arow = Apack + (size_t)(rbase + wi * 64 + mi * 16 + l15) * 256;
#pragma unroll
    for (int ks = 0; ks < 4; ++ks) {
      Ahi[mi][ks] = *(const u16x8*)(arow + ks * 32 + kg * 8);
      Alo[mi][ks] = *(const u16x8*)(arow + 128 + ks * 32 + kg * 8);
    }
  }

  // ---- top-20 lists (threads 0..127 own rows) ----
  float lv[20]; int li[20];
#pragma unroll
  for (int s = 0; s < 20; ++s) { lv[s] = -3.0e38f; li[s] = 0; }

  // ---- per-lane B-frag LDS byte offsets (XOR bank swizzle) ----
  int boff[4][4];
#pragma unroll
  for (int ni = 0; ni < 4; ++ni) {
    int jl = wj * 64 + ni * 16 + l15;
#pragma unroll
    for (int ksl = 0; ksl < 4; ++ksl) {
      int kbyte = (ksl * 32 + kg * 8) * 2;
      boff[ni][ksl] = jl * 256 + (kbyte ^ ((jl & 7) << 4));
    }
  }

  auto stage = [&](int chunk, int sb) {
    if (chunk >= 64) return;
    int S = chunk * 3 + sb;
    int soff = (sb == 1) ? 256 : 0;  // sb0:hi sb1:lo sb2:hi
    int jb = jstart + chunk * 128;
    char* base = Bs + ((S & 1) ? 32768 : 0);
#pragma unroll
    for (int i = 0; i < 8; ++i) {
      int L = (i * 256 + t) * 16;
      int row = L >> 8, bir = L & 255;
      gload_lds16((const char*)Bpack + (size_t)(jb + row) * 512 + soff + bir, base + L);
    }
  };

  stage(0, 0);
  __syncthreads();  // drains stage(0); init visible

  for (int chunk = 0; chunk < 64; ++chunk) {
    f32x4 acc[4][4];
#pragma unroll
    for (int mi = 0; mi < 4; ++mi)
#pragma unroll
      for (int ni = 0; ni < 4; ++ni) acc[mi][ni] = (f32x4){0.f, 0.f, 0.f, 0.f};

#pragma unroll
    for (int sb = 0; sb < 3; ++sb) {
      int S = chunk * 3 + sb;
      if (sb < 2) stage(chunk, sb + 1); else stage(chunk + 1, 0);
      const char* buf = Bs + ((S & 1) ? 32768 : 0);
#pragma unroll
      for (int ksl = 0; ksl < 4; ++ksl) {
        bf16x8 b[4];
#pragma unroll
        for (int ni = 0; ni < 4; ++ni)
          b[ni] = __builtin_bit_cast(bf16x8, *(const u16x8*)(buf + boff[ni][ksl]));
#pragma unroll
        for (int mi = 0; mi < 4; ++mi) {
          bf16x8 a = __builtin_bit_cast(bf16x8, (sb == 2) ? Alo[mi][ksl] : Ahi[mi][ksl]);
#pragma unroll
          for (int ni = 0; ni < 4; ++ni)
            acc[mi][ni] = __builtin_amdgcn_mfma_f32_16x16x32_bf16(a, b[ni], acc[mi][ni], 0, 0, 0);
        }
      }
      __syncthreads();  // staged slice landed; buf reads done
    }

    // ---- (A) per-row chunk max: in-lane over ni, cross-lane over l&15 ----
    float rm[4][4];
#pragma unroll
    for (int mi = 0; mi < 4; ++mi)
#pragma unroll
      for (int tq = 0; tq < 4; ++tq) {
        float v = fmaxf(fmaxf(acc[mi][0][tq], acc[mi][1][tq]),
                        fmaxf(acc[mi][2][tq], acc[mi][3][tq]));
        v = fmaxf(v, __shfl_xor(v, 1, 64));
        v = fmaxf(v, __shfl_xor(v, 2, 64));
        v = fmaxf(v, __shfl_xor(v, 4, 64));
        v = fmaxf(v, __shfl_xor(v, 8, 64));
        rm[mi][tq] = v;
      }
    {
      int sel = lane & 15;
      float outv = rm[0][0];
#pragma unroll
      for (int mi = 0; mi < 4; ++mi)
#pragma unroll
        for (int tq = 0; tq < 4; ++tq)
          if (sel == mi * 4 + tq) outv = rm[mi][tq];
      int row = wi * 64 + ((lane & 15) >> 2) * 16 + (lane >> 4) * 4 + (lane & 3);
      maxbuf[row * 2 + wj] = outv;
    }
    __syncthreads();

    // ---- (B) threshold test ----
    if (t < 128) {
      float cmax = fmaxf(maxbuf[t * 2], maxbuf[t * 2 + 1]);
      if (cmax > lv[19]) { flags[t] = 1; *anyflag = 1; }
    }
    __syncthreads();
    int af = *anyflag;  // uniform

    if (af) {
      // ---- (C) dump flagged rows' sim values ----
#pragma unroll
      for (int mi = 0; mi < 4; ++mi)
#pragma unroll
        for (int tq = 0; tq < 4; ++tq) {
          int row = wi * 64 + mi * 16 + kg * 4 + tq;
          if (flags[row]) {
#pragma unroll
            for (int ni = 0; ni < 4; ++ni)
              simbuf[row * 129 + wj * 64 + ni * 16 + l15] = acc[mi][ni][tq];
          }
        }
      __syncthreads();
      // ---- (D) sorted insert into register lists ----
      if (t < 128 && flags[t]) {
        int jb = jstart + chunk * 128;
        for (int c = 0; c < 128; ++c) {
          float v = simbuf[t * 129 + c];
          if (v > lv[19]) {
            float cv = v; int ci = jb + c;
#pragma unroll
            for (int s = 0; s < 20; ++s) {
              bool m = cv > lv[s];
              float tv = lv[s]; int ti = li[s];
              lv[s] = m ? cv : tv; li[s] = m ? ci : ti;
              cv = m ? tv : cv;   ci = m ? ti : ci;
            }
          }
        }
        flags[t] = 0;
      }
      if (t == 0) *anyflag = 0;
      __syncthreads();
    }
  }

  if (t < 128) {
    int row = rbase + t;
    float* pv = plv + ((size_t)jhalf * NDIM + row) * 20;
    int* pi = pli + ((size_t)jhalf * NDIM + row) * 20;
#pragma unroll
    for (int s = 0; s < 20; ++s) { pv[s] = lv[s]; pi[s] = li[s]; }
  }
}

// =====================================================================
// K2b: merge 2 sorted partial top-20 lists per row + softmax
// =====================================================================
__global__ __launch_bounds__(256) void k2b_merge(
    const float* __restrict__ plv, const int* __restrict__ pli,
    float* __restrict__ score, int* __restrict__ idx)
{
  int r = blockIdx.x * 256 + threadIdx.x;
  const float* v0 = plv + (size_t)r * 20;
  const float* v1 = plv + ((size_t)NDIM + r) * 20;
  const int* i0 = pli + (size_t)r * 20;
  const int* i1 = pli + ((size_t)NDIM + r) * 20;
  float* sc = score + (size_t)r * 20;
  int* ix = idx + (size_t)r * 20;

  int p0 = 0, p1 = 0;
  float vmax = fmaxf(v0[0], v1[0]);
  float sum = 0.f;
  for (int s = 0; s < 20; ++s) {
    float a = v0[p0], b = v1[p1];
    bool ta = (a >= b);
    float v = ta ? a : b;
    int j = ta ? i0[p0] : i1[p1];
    p0 += ta ? 1 : 0; p1 += ta ? 0 : 1;
    float e = expf(v - vmax);
    sum += e;
    sc[s] = e; ix[s] = j;
  }
  float inv = 1.0f / sum;
  for (int s = 0; s < 20; ++s) sc[s] *= inv;
}

// =====================================================================
// K3a: R[i] = sum_k score_k * relu(Am_i + Bm_{j_k})
// block 256 thr = 32 nodes x 8 lanes (16 channels each)
// =====================================================================
__global__ __launch_bounds__(256) void k3a_gather(
    const float* __restrict__ Am, const float* __restrict__ Bm,
    const float* __restrict__ score, const int* __restrict__ idx,
    float* __restrict__ R)
{
  int t = threadIdx.x;
  int node = blockIdx.x * 32 + (t >> 3);
  int c0 = (t & 7) * 16;
  const float* am = Am + (size_t)node * 128 + c0;
  fvec4 a[4], r[4];
#pragma unroll
  for (int i = 0; i < 4; ++i) {
    a[i] = *(const fvec4*)(am + 4 * i);
    r[i] = (fvec4){0.f, 0.f, 0.f, 0.f};
  }
  const float* sc = score + (size_t)node * 20;
  const int* ix = idx + (size_t)node * 20;
  for (int k = 0; k < 20; ++k) {
    int j = ix[k]; float s = sc[k];
    const float* bm = Bm + (size_t)j * 128 + c0;
#pragma unroll
    for (int i = 0; i < 4; ++i) {
      fvec4 b = *(const fvec4*)(bm + 4 * i);
#pragma unroll
      for (int q = 0; q < 4; ++q)
        r[i][q] += s * fmaxf(a[i][q] + b[q], 0.f);
    }
  }
  float* outp = R + (size_t)node * 128 + c0;
#pragma unroll
  for (int i = 0; i < 4; ++i) *(fvec4*)(outp + 4 * i) = r[i];
}

// =====================================================================
// K3b: out = x + relu(XU + (R@Wm2^T + bm2)@Wu1b^T)@Wu2^T + bu2
// 3-stage GEMM chain per 64-row tile.
// =====================================================================
__global__ __launch_bounds__(256, 1) void k3b_update(
    const float* __restrict__ R, const float* __restrict__ XU, const float* __restrict__ x,
    const float* __restrict__ Wm2, const float* __restrict__ bm2,
    const float* __restrict__ Wu1, const float* __restrict__ Wu2, const float* __restrict__ bu2,
    float* __restrict__ outg)
{
  extern __shared__ char lds[];
  float* in0 = (float*)lds;             // 32768
  float* in1 = (float*)(lds + 32768);   // 32768
  float* wT  = (float*)(lds + 65536);   // 65536

  const int t = threadIdx.x;
  const int rbase = blockIdx.x * 64;
  const int tr = t >> 4, tc = t & 15;

  // stage in0 from R (quad-swizzled)
#pragma unroll
  for (int i = 0; i < 8; ++i) {
    int flat = (i * 256 + t) * 4;
    int row = flat >> 7, c = flat & 127;
    fvec4 v = *(const fvec4*)(R + (size_t)(rbase + row) * 128 + c);
    *(fvec4*)(in0 + row * 128 + (((c >> 2) ^ ((row >> 2) & 7)) << 2)) = v;
  }

  for (int s = 0; s < 3; ++s) {
    const float* W; int wstride, coff;
    if (s == 0)      { W = Wm2; wstride = 128; coff = 0; }
    else if (s == 1) { W = Wu1; wstride = 256; coff = 128; }
    else             { W = Wu2; wstride = 128; coff = 0; }

    __syncthreads();
    {
      int co = t >> 1, c0 = (t & 1) * 64;
      const float* wr = W + (size_t)co * wstride + coff + c0;
#pragma unroll
      for (int i = 0; i < 16; ++i) {
        fvec4 v = *(const fvec4*)(wr + 4 * i);
        wT[(c0 + 4 * i + 0) * 128 + co] = v[0];
        wT[(c0 + 4 * i + 1) * 128 + co] = v[1];
        wT[(c0 + 4 * i + 2) * 128 + co] = v[2];
        wT[(c0 + 4 * i + 3) * 128 + co] = v[3];
      }
    }
    __syncthreads();

    const float* in = (s == 1) ? in1 : in0;
    float acc[4][8];
#pragma unroll
    for (int rr = 0; rr < 4; ++rr)
#pragma unroll
      for (int i = 0; i < 8; ++i) acc[rr][i] = 0.f;

    for (int cq = 0; cq < 32; ++cq) {
      fvec4 xv[4];
#pragma unroll
      for (int rr = 0; rr < 4; ++rr)
        xv[rr] = *(const fvec4*)(in + (tr * 4 + rr) * 128 + ((cq ^ (tr & 7)) << 2));
#pragma unroll
      for (int j = 0; j < 4; ++j) {
        int c = cq * 4 + j;
        fvec4 wa = *(const fvec4*)(wT + c * 128 + tc * 4);
        fvec4 wb = *(const fvec4*)(wT + c * 128 + 64 + tc * 4);
#pragma unroll
        for (int rr = 0; rr < 4; ++rr) {
          float xj = xv[rr][j];
#pragma unroll
          for (int i = 0; i < 4; ++i) {
            acc[rr][i]     += xj * wa[i];
            acc[rr][4 + i] += xj * wb[i];
          }
        }
      }
    }

#pragma unroll
    for (int rr = 0; rr < 4; ++rr) {
      int row = rbase + tr * 4 + rr;
      int lrow = tr * 4 + rr;
      int q0 = tc ^ (tr & 7);
      int q1 = (16 + tc) ^ (tr & 7);
      if (s == 0) {  // + bm2 -> in1
        fvec4 b0 = *(const fvec4*)(bm2 + tc * 4);
        fvec4 b1 = *(const fvec4*)(bm2 + 64 + tc * 4);
        fvec4 w0, w1;
#pragma unroll
        for (int i = 0; i < 4; ++i) { w0[i] = acc[rr][i] + b0[i]; w1[i] = acc[rr][4 + i] + b1[i]; }
        *(fvec4*)(in1 + lrow * 128 + q0 * 4) = w0;
        *(fvec4*)(in1 + lrow * 128 + q1 * 4) = w1;
      } else if (s == 1) {  // relu(XU + acc) -> in0
        fvec4 x0 = *(const fvec4*)(XU + (size_t)row * 128 + tc * 4);
        fvec4 x1 = *(const fvec4*)(XU + (size_t)row * 128 + 64 + tc * 4);
        fvec4 w0, w1;
#pragma unroll
        for (int i = 0; i < 4; ++i) {
          w0[i] = fmaxf(acc[rr][i] + x0[i], 0.f);
          w1[i] = fmaxf(acc[rr][4 + i] + x1[i], 0.f);
        }
        *(fvec4*)(in0 + lrow * 128 + q0 * 4) = w0;
        *(fvec4*)(in0 + lrow * 128 + q1 * 4) = w1;
      } else {  // out = x + acc + bu2
        fvec4 b0 = *(const fvec4*)(bu2 + tc * 4);
        fvec4 b1 = *(const fvec4*)(bu2 + 64 + tc * 4);
        fvec4 x0 = *(const fvec4*)(x + (size_t)row * 128 + tc * 4);
        fvec4 x1 = *(const fvec4*)(x + (size_t)row * 128 + 64 + tc * 4);
        fvec4 w0, w1;
#pragma unroll
        for (int i = 0; i < 4; ++i) {
          w0[i] = x0[i] + acc[rr][i] + b0[i];
          w1[i] = x1[i] + acc[rr][4 + i] + b1[i];
        }
        *(fvec4*)(outg + (size_t)row * 128 + tc * 4) = w0;
        *(fvec4*)(outg + (size_t)row * 128 + 64 + tc * 4) = w1;
      }
    }
    __syncthreads();
  }
}

// =====================================================================
// launch
// =====================================================================
extern "C" void kernel_launch(void* const* d_in, const int* in_sizes, int n_in,
                              void* d_out, int out_size, void* d_ws, size_t ws_size,
                              hipStream_t stream) {
  const float* x   = (const float*)d_in[0];
  const float* Wq  = (const float*)d_in[1];
  const float* bq  = (const float*)d_in[2];
  const float* Wk  = (const float*)d_in[3];
  const float* bk  = (const float*)d_in[4];
  const float* Wm1 = (const float*)d_in[5];
  const float* bm1 = (const float*)d_in[6];
  const float* Wm2 = (const float*)d_in[7];
  const float* bm2 = (const float*)d_in[8];
  const float* Wu1 = (const float*)d_in[9];
  const float* bu1 = (const float*)d_in[10];
  const float* Wu2 = (const float*)d_in[11];
  const float* bu2 = (const float*)d_in[12];
  float* outp = (float*)d_out;

  const size_t NN = NDIM;
  char* w = (char*)d_ws;
  unsigned short* Apack = (unsigned short*)w; w += NN * 256 * 2;
  unsigned short* Bpack = (unsigned short*)w; w += NN * 256 * 2;
  float* Am = (float*)w; w += NN * 128 * 4;
  float* Bm = (float*)w; w += NN * 128 * 4;
  float* XU = (float*)w; w += NN * 128 * 4;
  float* plv = (float*)w; w += 2 * NN * 20 * 4;
  int* pli = (int*)w; w += 2 * NN * 20 * 4;
  float* score = (float*)w; w += NN * 20 * 4;
  int* idxb = (int*)w; w += NN * 20 * 4;
  float* R = (float*)w; w += NN * 128 * 4;

  hipFuncSetAttribute((const void*)k1_linears, hipFuncAttributeMaxDynamicSharedMemorySize, 98304);
  hipFuncSetAttribute((const void*)k2_simtopk, hipFuncAttributeMaxDynamicSharedMemorySize, 132800);
  hipFuncSetAttribute((const void*)k3b_update, hipFuncAttributeMaxDynamicSharedMemorySize, 131072);

  k1_linears<<<256, 256, 98304, stream>>>(x, Wq, bq, Wk, bk, Wm1, bm1, Wu1, bu1,
                                          Apack, Bpack, Am, Bm, XU);
  k2_simtopk<<<256, 256, 132800, stream>>>(Apack, Bpack, plv, pli);
  k2b_merge<<<64, 256, 0, stream>>>(plv, pli, score, idxb);
  k3a_gather<<<512, 256, 0, stream>>>(Am, Bm, score, idxb, R);
  k3b_update<<<256, 256, 131072, stream>>>(R, XU, x, Wm2, bm2, Wu1, Wu2, bu2, outp);
}

// Round 2
// 812.609 us; speedup vs baseline: 2.6850x; 2.6850x over previous
//
#include <hip/hip_runtime.h>
#include <stdint.h>

#define NDIM 16384

typedef float  fvec4  __attribute__((ext_vector_type(4)));
typedef float  f32x4  __attribute__((ext_vector_type(4)));
typedef __bf16 bf16x8 __attribute__((ext_vector_type(8)));
typedef unsigned short u16x8 __attribute__((ext_vector_type(8)));
typedef unsigned short u16x4 __attribute__((ext_vector_type(4)));

static_assert(sizeof(bf16x8) == 16, "bf16x8 must be 16B");
static_assert(sizeof(u16x8) == 16, "u16x8 must be 16B");

// ---------- helpers ----------

__device__ __forceinline__ unsigned short bf16r(float x) {
  unsigned u = __builtin_bit_cast(unsigned, x);
  return (unsigned short)((u + 0x7FFFu + ((u >> 16) & 1u)) >> 16);
}

__device__ __forceinline__ void split2(float v, unsigned short& h, unsigned short& l) {
  h = bf16r(v);
  float hf = __builtin_bit_cast(float, (unsigned)h << 16);
  l = bf16r(v - hf);
}

// global -> LDS direct copy, 16B per lane (linear dest per wave)
__device__ __forceinline__ void gload_lds16(const void* g, void* l) {
  typedef __attribute__((address_space(1))) const unsigned int gas_u32;
  typedef __attribute__((address_space(3))) unsigned int las_u32;
  __builtin_amdgcn_global_load_lds((gas_u32*)(uintptr_t)g,
                                   (las_u32*)(unsigned)(uintptr_t)l, 16, 0, 0);
}

#define MEMFENCE asm volatile("" ::: "memory")
#define BARRIER  do { MEMFENCE; __builtin_amdgcn_s_barrier(); MEMFENCE; } while (0)

// =====================================================================
// K1: fused linears: q->Bpack(swizzled split bf16), k->Apack(split bf16),
//     Am = x@Wm1a^T, Bm = x@Wm1b^T + bm1, XU = x@Wu1a^T + bu1
// =====================================================================
__global__ __launch_bounds__(256, 1) void k1_linears(
    const float* __restrict__ x,
    const float* __restrict__ Wq, const float* __restrict__ bq,
    const float* __restrict__ Wk, const float* __restrict__ bk,
    const float* __restrict__ Wm1, const float* __restrict__ bm1,
    const float* __restrict__ Wu1, const float* __restrict__ bu1,
    unsigned short* __restrict__ Apack, unsigned short* __restrict__ Bpack,
    float* __restrict__ Am, float* __restrict__ Bm, float* __restrict__ XU)
{
  extern __shared__ char lds[];
  float* xs = (float*)lds;              // 32768 B, [64][128] quad-swizzled
  float* wT = (float*)(lds + 32768);    // 65536 B, [c][co]

  const int t = threadIdx.x;
  const int rbase = blockIdx.x * 64;
  const int tr = t >> 4, tc = t & 15;

#pragma unroll
  for (int i = 0; i < 8; ++i) {
    int flat = (i * 256 + t) * 4;
    int row = flat >> 7, c = flat & 127;
    fvec4 v = *(const fvec4*)(x + (size_t)(rbase + row) * 128 + c);
    int q = (c >> 2) ^ ((row >> 2) & 7);
    *(fvec4*)(xs + row * 128 + q * 4) = v;
  }

  for (int s = 0; s < 5; ++s) {
    const float* W; int wstride, coff; const float* bias;
    if (s == 0)      { W = Wq;  wstride = 128; coff = 0;   bias = bq; }
    else if (s == 1) { W = Wk;  wstride = 128; coff = 0;   bias = bk; }
    else if (s == 2) { W = Wm1; wstride = 256; coff = 0;   bias = nullptr; }
    else if (s == 3) { W = Wm1; wstride = 256; coff = 128; bias = bm1; }
    else             { W = Wu1; wstride = 256; coff = 0;   bias = bu1; }

    __syncthreads();
    {
      int co = t >> 1, c0 = (t & 1) * 64;
      const float* wr = W + (size_t)co * wstride + coff + c0;
#pragma unroll
      for (int i = 0; i < 16; ++i) {
        fvec4 v = *(const fvec4*)(wr + 4 * i);
        wT[(c0 + 4 * i + 0) * 128 + co] = v[0];
        wT[(c0 + 4 * i + 1) * 128 + co] = v[1];
        wT[(c0 + 4 * i + 2) * 128 + co] = v[2];
        wT[(c0 + 4 * i + 3) * 128 + co] = v[3];
      }
    }
    __syncthreads();

    float acc[4][8];
#pragma unroll
    for (int rr = 0; rr < 4; ++rr)
#pragma unroll
      for (int i = 0; i < 8; ++i) acc[rr][i] = 0.f;

    for (int cq = 0; cq < 32; ++cq) {
      fvec4 xv[4];
#pragma unroll
      for (int rr = 0; rr < 4; ++rr)
        xv[rr] = *(const fvec4*)(xs + (tr * 4 + rr) * 128 + ((cq ^ (tr & 7)) << 2));
#pragma unroll
      for (int j = 0; j < 4; ++j) {
        int c = cq * 4 + j;
        fvec4 wa = *(const fvec4*)(wT + c * 128 + tc * 4);
        fvec4 wb = *(const fvec4*)(wT + c * 128 + 64 + tc * 4);
#pragma unroll
        for (int rr = 0; rr < 4; ++rr) {
          float xj = xv[rr][j];
#pragma unroll
          for (int i = 0; i < 4; ++i) {
            acc[rr][i]     += xj * wa[i];
            acc[rr][4 + i] += xj * wb[i];
          }
        }
      }
    }

    float ba[4] = {0, 0, 0, 0}, bb[4] = {0, 0, 0, 0};
    if (bias) {
      fvec4 t0 = *(const fvec4*)(bias + tc * 4);
      fvec4 t1 = *(const fvec4*)(bias + 64 + tc * 4);
#pragma unroll
      for (int i = 0; i < 4; ++i) { ba[i] = t0[i]; bb[i] = t1[i]; }
    }

#pragma unroll
    for (int rr = 0; rr < 4; ++rr) {
      int row = rbase + tr * 4 + rr;
      float v0[4], v1[4];
#pragma unroll
      for (int i = 0; i < 4; ++i) {
        v0[i] = acc[rr][i] + ba[i];
        v1[i] = acc[rr][4 + i] + bb[i];
      }
      if (s >= 2) {
        float* dst = (s == 2 ? Am : (s == 3 ? Bm : XU)) + (size_t)row * 128;
        fvec4 w0 = {v0[0], v0[1], v0[2], v0[3]};
        fvec4 w1 = {v1[0], v1[1], v1[2], v1[3]};
        *(fvec4*)(dst + tc * 4) = w0;
        *(fvec4*)(dst + 64 + tc * 4) = w1;
      } else {
        unsigned short h0[4], l0[4], h1[4], l1[4];
#pragma unroll
        for (int i = 0; i < 4; ++i) { split2(v0[i], h0[i], l0[i]); split2(v1[i], h1[i], l1[i]); }
        u16x4 H0 = {h0[0], h0[1], h0[2], h0[3]};
        u16x4 H1 = {h1[0], h1[1], h1[2], h1[3]};
        u16x4 L0 = {l0[0], l0[1], l0[2], l0[3]};
        u16x4 L1 = {l1[0], l1[1], l1[2], l1[3]};
        if (s == 1) {
          unsigned short* dst = Apack + (size_t)row * 256;
          *(u16x4*)(dst + tc * 4) = H0;
          *(u16x4*)(dst + 64 + tc * 4) = H1;
          *(u16x4*)(dst + 128 + tc * 4) = L0;
          *(u16x4*)(dst + 192 + tc * 4) = L1;
        } else {
          int jm = row & 7;
          int p0 = (((tc >> 1) ^ jm) << 3) | ((tc & 1) << 2);
          int p1 = (((8 + (tc >> 1)) ^ jm) << 3) | ((tc & 1) << 2);
          unsigned short* dst = Bpack + (size_t)row * 256;
          *(u16x4*)(dst + p0) = H0;
          *(u16x4*)(dst + p1) = H1;
          *(u16x4*)(dst + 128 + p0) = L0;
          *(u16x4*)(dst + 128 + p1) = L1;
        }
      }
    }
  }
}

// =====================================================================
// K2: fused split-bf16 GEMM (K=384) + streaming top-20 per row.
// grid 256 = 128 row-tiles x 2 j-halves. 4 waves (2x2), wave tile 64x64.
// Counted-vmcnt double-buffered staging; always-dump + batched bit-scan.
// LDS: Bs 2x32768 | simbuf [128 rows][132 dwords] (528B stride, 16B-aligned)
// =====================================================================
__global__ __launch_bounds__(256, 1) void k2_simtopk(
    const unsigned short* __restrict__ Apack, const unsigned short* __restrict__ Bpack,
    float* __restrict__ plv, int* __restrict__ pli)
{
  extern __shared__ char lds[];
  char* Bs = lds;                            // 2 x 32768
  float* simbuf = (float*)(lds + 65536);     // 128 * 528 B = 67584

  const int t = threadIdx.x;
  const int lane = t & 63, wid = t >> 6;
  const int wi = wid >> 1, wj = wid & 1;
  const int tile = blockIdx.x >> 1, jhalf = blockIdx.x & 1;
  const int rbase = tile * 128;
  const int jstart = jhalf * 8192;
  const int l15 = lane & 15, kg = lane >> 4;

  // ---- A fragments in registers ----
  u16x8 Ahi[4][4], Alo[4][4];
#pragma unroll
  for (int mi = 0; mi < 4; ++mi) {
    const unsigned short* arow = Apack + (size_t)(rbase + wi * 64 + mi * 16 + l15) * 256;
#pragma unroll
    for (int ks = 0; ks < 4; ++ks) {
      Ahi[mi][ks] = *(const u16x8*)(arow + ks * 32 + kg * 8);
      Alo[mi][ks] = *(const u16x8*)(arow + 128 + ks * 32 + kg * 8);
    }
  }

  // ---- top-20 list: owner = lane<32 of each wave, row o = wid*32+lane ----
  const bool owner = (lane < 32);
  const int orow = wid * 32 + lane;   // valid when owner
  float lv[20]; int li[20];
#pragma unroll
  for (int s = 0; s < 20; ++s) { lv[s] = -3.0e38f; li[s] = 0; }

  // ---- per-lane B-frag LDS byte offsets (XOR bank swizzle) ----
  int boff[4][4];
#pragma unroll
  for (int ni = 0; ni < 4; ++ni) {
    int jl = wj * 64 + ni * 16 + l15;
#pragma unroll
    for (int ksl = 0; ksl < 4; ++ksl) {
      int kbyte = (ksl * 32 + kg * 8) * 2;
      boff[ni][ksl] = jl * 256 + (kbyte ^ ((jl & 7) << 4));
    }
  }

  auto stage = [&](int S) {           // slice S = chunk*3 + sb
    int chunk = S / 3;
    if (chunk >= 64) return;
    int sb = S - chunk * 3;
    int soff = (sb == 1) ? 256 : 0;   // sb0:hi sb1:lo sb2:hi
    int jb = jstart + chunk * 128;
    char* base = Bs + ((S & 1) ? 32768 : 0);
#pragma unroll
    for (int i = 0; i < 8; ++i) {
      int L = (i * 256 + t) * 16;
      int row = L >> 8, bir = L & 255;
      gload_lds16((const char*)Bpack + (size_t)(jb + row) * 512 + soff + bir, base + L);
    }
  };

  f32x4 acc[4][4];

  auto mfma_sb = [&](const u16x8 (&A)[4][4], const char* buf) {
#pragma unroll
    for (int ksl = 0; ksl < 4; ++ksl) {
      bf16x8 b[4];
#pragma unroll
      for (int ni = 0; ni < 4; ++ni)
        b[ni] = __builtin_bit_cast(bf16x8, *(const u16x8*)(buf + boff[ni][ksl]));
#pragma unroll
      for (int mi = 0; mi < 4; ++mi) {
        bf16x8 a = __builtin_bit_cast(bf16x8, A[mi][ksl]);
#pragma unroll
        for (int ni = 0; ni < 4; ++ni)
          acc[mi][ni] = __builtin_amdgcn_mfma_f32_16x16x32_bf16(a, b[ni], acc[mi][ni], 0, 0, 0);
      }
    }
  };

  // prologue: two slices in flight
  stage(0);
  stage(1);

  for (int chunk = 0; chunk < 64; ++chunk) {
#pragma unroll
    for (int sb = 0; sb < 3; ++sb) {
      const int S = chunk * 3 + sb;
      // wait own slice-S loads (8 of slice S+1 may stay in flight), then sync
      asm volatile("s_waitcnt vmcnt(8)" ::: "memory");
      BARRIER;

      if (sb == 0) {
#pragma unroll
        for (int mi = 0; mi < 4; ++mi)
#pragma unroll
          for (int ni = 0; ni < 4; ++ni) acc[mi][ni] = (f32x4){0.f, 0.f, 0.f, 0.f};
      }

      const char* buf = Bs + ((S & 1) ? 32768 : 0);
      if (sb == 2) mfma_sb(Alo, buf); else mfma_sb(Ahi, buf);

      if (sb < 2) {
        BARRIER;          // all reads of buf done -> safe to overwrite 2 slices later
        stage(S + 2);
      } else {
        // ---- dump all rows' sim values ----
#pragma unroll
        for (int mi = 0; mi < 4; ++mi)
#pragma unroll
          for (int ni = 0; ni < 4; ++ni)
#pragma unroll
            for (int tq = 0; tq < 4; ++tq) {
              int row = wi * 64 + mi * 16 + kg * 4 + tq;
              int col = wj * 64 + ni * 16 + l15;
              simbuf[row * 132 + col] = acc[mi][ni][tq];
            }
        asm volatile("s_waitcnt lgkmcnt(0)" ::: "memory");  // dump visible
        BARRIER;          // dump visible to owners; buf reads done
        stage(S + 2);     // prefetch before scan so HBM latency hides under it

        // ---- batched per-row scan + top-20 insert ----
        if (owner) {
          const float* rp = simbuf + orow * 132;
          const int jb = jstart + chunk * 128;
#pragma unroll
          for (int g = 0; g < 4; ++g) {
            fvec4 q[8];
#pragma unroll
            for (int i = 0; i < 8; ++i)
              q[i] = *(const fvec4*)(rp + g * 32 + i * 4);
            unsigned m = 0;
            float thr = lv[19];
#pragma unroll
            for (int i = 0; i < 8; ++i)
#pragma unroll
              for (int k = 0; k < 4; ++k)
                m |= (q[i][k] > thr) ? (1u << (i * 4 + k)) : 0u;
            while (m) {
              int b = __builtin_ctz(m); m &= m - 1;
              int c = g * 32 + b;
              float v = rp[c];
              if (v > lv[19]) {
                float cv = v; int ci = jb + c;
#pragma unroll
                for (int s = 0; s < 20; ++s) {
                  bool mm = cv > lv[s];
                  float tv = lv[s]; int ti = li[s];
                  lv[s] = mm ? cv : tv; li[s] = mm ? ci : ti;
                  cv = mm ? tv : cv;   ci = mm ? ti : ci;
                }
              }
            }
          }
        }
        BARRIER;          // scan done before next chunk's dump overwrites simbuf
      }
    }
  }

  if (owner) {
    int row = rbase + orow;
    float* pv = plv + ((size_t)jhalf * NDIM + row) * 20;
    int* pi = pli + ((size_t)jhalf * NDIM + row) * 20;
#pragma unroll
    for (int s = 0; s < 20; ++s) { pv[s] = lv[s]; pi[s] = li[s]; }
  }
}

// =====================================================================
// K2b: merge 2 sorted partial top-20 lists per row + softmax
// =====================================================================
__global__ __launch_bounds__(256) void k2b_merge(
    const float* __restrict__ plv, const int* __restrict__ pli,
    float* __restrict__ score, int* __restrict__ idx)
{
  int r = blockIdx.x * 256 + threadIdx.x;
  const float* v0 = plv + (size_t)r * 20;
  const float* v1 = plv + ((size_t)NDIM + r) * 20;
  const int* i0 = pli + (size_t)r * 20;
  const int* i1 = pli + ((size_t)NDIM + r) * 20;
  float* sc = score + (size_t)r * 20;
  int* ix = idx + (size_t)r * 20;

  int p0 = 0, p1 = 0;
  float vmax = fmaxf(v0[0], v1[0]);
  float sum = 0.f;
  for (int s = 0; s < 20; ++s) {
    float a = v0[p0], b = v1[p1];
    bool ta = (a >= b);
    float v = ta ? a : b;
    int j = ta ? i0[p0] : i1[p1];
    p0 += ta ? 1 : 0; p1 += ta ? 0 : 1;
    float e = expf(v - vmax);
    sum += e;
    sc[s] = e; ix[s] = j;
  }
  float inv = 1.0f / sum;
  for (int s = 0; s < 20; ++s) sc[s] *= inv;
}

// =====================================================================
// K3a: R[i] = sum_k score_k * relu(Am_i + Bm_{j_k})
// =====================================================================
__global__ __launch_bounds__(256) void k3a_gather(
    const float* __restrict__ Am, const float* __restrict__ Bm,
    const float* __restrict__ score, const int* __restrict__ idx,
    float* __restrict__ R)
{
  int t = threadIdx.x;
  int node = blockIdx.x * 32 + (t >> 3);
  int c0 = (t & 7) * 16;
  const float* am = Am + (size_t)node * 128 + c0;
  fvec4 a[4], r[4];
#pragma unroll
  for (int i = 0; i < 4; ++i) {
    a[i] = *(const fvec4*)(am + 4 * i);
    r[i] = (fvec4){0.f, 0.f, 0.f, 0.f};
  }
  const float* sc = score + (size_t)node * 20;
  const int* ix = idx + (size_t)node * 20;
  for (int k = 0; k < 20; ++k) {
    int j = ix[k]; float s = sc[k];
    const float* bm = Bm + (size_t)j * 128 + c0;
#pragma unroll
    for (int i = 0; i < 4; ++i) {
      fvec4 b = *(const fvec4*)(bm + 4 * i);
#pragma unroll
      for (int q = 0; q < 4; ++q)
        r[i][q] += s * fmaxf(a[i][q] + b[q], 0.f);
    }
  }
  float* outp = R + (size_t)node * 128 + c0;
#pragma unroll
  for (int i = 0; i < 4; ++i) *(fvec4*)(outp + 4 * i) = r[i];
}

// =====================================================================
// K3b: out = x + relu(XU + (R@Wm2^T + bm2)@Wu1b^T)@Wu2^T + bu2
// =====================================================================
__global__ __launch_bounds__(256, 1) void k3b_update(
    const float* __restrict__ R, const float* __restrict__ XU, const float* __restrict__ x,
    const float* __restrict__ Wm2, const float* __restrict__ bm2,
    const float* __restrict__ Wu1, const float* __restrict__ Wu2, const float* __restrict__ bu2,
    float* __restrict__ outg)
{
  extern __shared__ char lds[];
  float* in0 = (float*)lds;             // 32768
  float* in1 = (float*)(lds + 32768);   // 32768
  float* wT  = (float*)(lds + 65536);   // 65536

  const int t = threadIdx.x;
  const int rbase = blockIdx.x * 64;
  const int tr = t >> 4, tc = t & 15;

#pragma unroll
  for (int i = 0; i < 8; ++i) {
    int flat = (i * 256 + t) * 4;
    int row = flat >> 7, c = flat & 127;
    fvec4 v = *(const fvec4*)(R + (size_t)(rbase + row) * 128 + c);
    *(fvec4*)(in0 + row * 128 + (((c >> 2) ^ ((row >> 2) & 7)) << 2)) = v;
  }

  for (int s = 0; s < 3; ++s) {
    const float* W; int wstride, coff;
    if (s == 0)      { W = Wm2; wstride = 128; coff = 0; }
    else if (s == 1) { W = Wu1; wstride = 256; coff = 128; }
    else             { W = Wu2; wstride = 128; coff = 0; }

    __syncthreads();
    {
      int co = t >> 1, c0 = (t & 1) * 64;
      const float* wr = W + (size_t)co * wstride + coff + c0;
#pragma unroll
      for (int i = 0; i < 16; ++i) {
        fvec4 v = *(const fvec4*)(wr + 4 * i);
        wT[(c0 + 4 * i + 0) * 128 + co] = v[0];
        wT[(c0 + 4 * i + 1) * 128 + co] = v[1];
        wT[(c0 + 4 * i + 2) * 128 + co] = v[2];
        wT[(c0 + 4 * i + 3) * 128 + co] = v[3];
      }
    }
    __syncthreads();

    const float* in = (s == 1) ? in1 : in0;
    float acc[4][8];
#pragma unroll
    for (int rr = 0; rr < 4; ++rr)
#pragma unroll
      for (int i = 0; i < 8; ++i) acc[rr][i] = 0.f;

    for (int cq = 0; cq < 32; ++cq) {
      fvec4 xv[4];
#pragma unroll
      for (int rr = 0; rr < 4; ++rr)
        xv[rr] = *(const fvec4*)(in + (tr * 4 + rr) * 128 + ((cq ^ (tr & 7)) << 2));
#pragma unroll
      for (int j = 0; j < 4; ++j) {
        int c = cq * 4 + j;
        fvec4 wa = *(const fvec4*)(wT + c * 128 + tc * 4);
        fvec4 wb = *(const fvec4*)(wT + c * 128 + 64 + tc * 4);
#pragma unroll
        for (int rr = 0; rr < 4; ++rr) {
          float xj = xv[rr][j];
#pragma unroll
          for (int i = 0; i < 4; ++i) {
            acc[rr][i]     += xj * wa[i];
            acc[rr][4 + i] += xj * wb[i];
          }
        }
      }
    }

#pragma unroll
    for (int rr = 0; rr < 4; ++rr) {
      int row = rbase + tr * 4 + rr;
      int lrow = tr * 4 + rr;
      int q0 = tc ^ (tr & 7);
      int q1 = (16 + tc) ^ (tr & 7);
      if (s == 0) {
        fvec4 b0 = *(const fvec4*)(bm2 + tc * 4);
        fvec4 b1 = *(const fvec4*)(bm2 + 64 + tc * 4);
        fvec4 w0, w1;
#pragma unroll
        for (int i = 0; i < 4; ++i) { w0[i] = acc[rr][i] + b0[i]; w1[i] = acc[rr][4 + i] + b1[i]; }
        *(fvec4*)(in1 + lrow * 128 + q0 * 4) = w0;
        *(fvec4*)(in1 + lrow * 128 + q1 * 4) = w1;
      } else if (s == 1) {
        fvec4 x0 = *(const fvec4*)(XU + (size_t)row * 128 + tc * 4);
        fvec4 x1 = *(const fvec4*)(XU + (size_t)row * 128 + 64 + tc * 4);
        fvec4 w0, w1;
#pragma unroll
        for (int i = 0; i < 4; ++i) {
          w0[i] = fmaxf(acc[rr][i] + x0[i], 0.f);
          w1[i] = fmaxf(acc[rr][4 + i] + x1[i], 0.f);
        }
        *(fvec4*)(in0 + lrow * 128 + q0 * 4) = w0;
        *(fvec4*)(in0 + lrow * 128 + q1 * 4) = w1;
      } else {
        fvec4 b0 = *(const fvec4*)(bu2 + tc * 4);
        fvec4 b1 = *(const fvec4*)(bu2 + 64 + tc * 4);
        fvec4 x0 = *(const fvec4*)(x + (size_t)row * 128 + tc * 4);
        fvec4 x1 = *(const fvec4*)(x + (size_t)row * 128 + 64 + tc * 4);
        fvec4 w0, w1;
#pragma unroll
        for (int i = 0; i < 4; ++i) {
          w0[i] = x0[i] + acc[rr][i] + b0[i];
          w1[i] = x1[i] + acc[rr][4 + i] + b1[i];
        }
        *(fvec4*)(outg + (size_t)row * 128 + tc * 4) = w0;
        *(fvec4*)(outg + (size_t)row * 128 + 64 + tc * 4) = w1;
      }
    }
    __syncthreads();
  }
}

// =====================================================================
// launch
// =====================================================================
extern "C" void kernel_launch(void* const* d_in, const int* in_sizes, int n_in,
                              void* d_out, int out_size, void* d_ws, size_t ws_size,
                              hipStream_t stream) {
  const float* x   = (const float*)d_in[0];
  const float* Wq  = (const float*)d_in[1];
  const float* bq  = (const float*)d_in[2];
  const float* Wk  = (const float*)d_in[3];
  const float* bk  = (const float*)d_in[4];
  const float* Wm1 = (const float*)d_in[5];
  const float* bm1 = (const float*)d_in[6];
  const float* Wm2 = (const float*)d_in[7];
  const float* bm2 = (const float*)d_in[8];
  const float* Wu1 = (const float*)d_in[9];
  const float* bu1 = (const float*)d_in[10];
  const float* Wu2 = (const float*)d_in[11];
  const float* bu2 = (const float*)d_in[12];
  float* outp = (float*)d_out;

  const size_t NN = NDIM;
  char* w = (char*)d_ws;
  unsigned short* Apack = (unsigned short*)w; w += NN * 256 * 2;
  unsigned short* Bpack = (unsigned short*)w; w += NN * 256 * 2;
  float* Am = (float*)w; w += NN * 128 * 4;
  float* Bm = (float*)w; w += NN * 128 * 4;
  float* XU = (float*)w; w += NN * 128 * 4;
  float* plv = (float*)w; w += 2 * NN * 20 * 4;
  int* pli = (int*)w; w += 2 * NN * 20 * 4;
  float* score = (float*)w; w += NN * 20 * 4;
  int* idxb = (int*)w; w += NN * 20 * 4;
  float* R = (float*)w; w += NN * 128 * 4;

  hipFuncSetAttribute((const void*)k1_linears, hipFuncAttributeMaxDynamicSharedMemorySize, 98304);
  hipFuncSetAttribute((const void*)k2_simtopk, hipFuncAttributeMaxDynamicSharedMemorySize, 133120);
  hipFuncSetAttribute((const void*)k3b_update, hipFuncAttributeMaxDynamicSharedMemorySize, 131072);

  k1_linears<<<256, 256, 98304, stream>>>(x, Wq, bq, Wk, bk, Wm1, bm1, Wu1, bu1,
                                          Apack, Bpack, Am, Bm, XU);
  k2_simtopk<<<256, 256, 133120, stream>>>(Apack, Bpack, plv, pli);
  k2b_merge<<<64, 256, 0, stream>>>(plv, pli, score, idxb);
  k3a_gather<<<512, 256, 0, stream>>>(Am, Bm, score, idxb, R);
  k3b_update<<<256, 256, 131072, stream>>>(R, XU, x, Wm2, bm2, Wu1, Wu2, bu2, outp);
}